// Round 13
// baseline (406.004 us; speedup 1.0000x reference)
//
#include <hip/hip_runtime.h>

// ---------------------------------------------------------------------------
// CormorantCGProduct on MI355X — round 13: BLOCK-PER-N, amortized prologue.
// Inputs (INTERLEAVED): A0,B0,A1,B1,A2,B2,A3,B3, each fp32 (2, N, 2l+1, 16).
// Output: concat over L=0..3 of (2, N, 2L+1, CH_L), CH_L = 256*npairs_L.
//
// Evidence: r3/r11/r12 (three different structures) all give prod ~130-135 µs
// (2.5 TB/s effective) — store ORDER is not the limiter.  Remaining
// hypotheses: (a) per-wave prologue dominates (2 stores per wave amortize
// nothing), or (b) ~2.5 TB/s compute+store ceiling.  This version: one block
// per n (512 thr, 8 waves); each wave processes ~19 of the n-row's 156
// (L,z,pair) segments -> ~39 stores/wave, A/B L1-hot across segments,
// per-segment cost = 2 scalar table loads + uniform switch + verified body.
// Outcome decides: collapse => (a); ~270-290 => store roofline over timed
// fill; unchanged => (b) ceiling.
// ---------------------------------------------------------------------------

typedef float f32x4 __attribute__((ext_vector_type(4)));

// ---- compile-time Clebsch-Gordan (same f64 formula as reference) ------
constexpr double dfactc(int n) {
    double r = 1.0;
    for (int i = 2; i <= n; ++i) r *= (double)i;
    return r;
}

constexpr double csqrt(double x) {
    if (x <= 0.0) return 0.0;
    double g = x >= 1.0 ? x : 1.0;
    for (int i = 0; i < 32; ++i) g = 0.5 * (g + x / g);
    return g;
}

constexpr double cg_coef_c(int j1, int m1, int j2, int m2, int j, int m) {
    if (m1 + m2 != m) return 0.0;
    double pref = csqrt((double)(2 * j + 1)
        * dfactc(j + j1 - j2) * dfactc(j - j1 + j2) * dfactc(j1 + j2 - j)
        / dfactc(j1 + j2 + j + 1)
        * dfactc(j + m) * dfactc(j - m) * dfactc(j1 - m1) * dfactc(j1 + m1)
        * dfactc(j2 - m2) * dfactc(j2 + m2));
    int kmin = 0;
    if (j2 - j - m1 > kmin) kmin = j2 - j - m1;
    if (j1 - j + m2 > kmin) kmin = j1 - j + m2;
    int kmax = j1 + j2 - j;
    if (j1 - m1 < kmax) kmax = j1 - m1;
    if (j2 + m2 < kmax) kmax = j2 + m2;
    double s = 0.0;
    for (int k = kmin; k <= kmax; ++k) {
        double d = dfactc(k) * dfactc(j1 + j2 - j - k) * dfactc(j1 - m1 - k)
                 * dfactc(j2 + m2 - k) * dfactc(j - j2 + m1 + k)
                 * dfactc(j - j1 - m2 + k);
        s += (k & 1) ? (-1.0 / d) : (1.0 / d);
    }
    return pref * s;
}

// ---- per-L pair lists (l1-major, l2-minor — reference concat order) ---
struct PairList {
    int l1[11], l2[11], off[11];
    int np, total;
};

constexpr PairList plist(int L) {
    PairList P{};
    int np = 0, off = 0;
    for (int a = 0; a <= 3; ++a)
    for (int b = 0; b <= 3; ++b) {
        int lo = (a > b) ? (a - b) : (b - a);
        int hi = (a + b < 3) ? (a + b) : 3;
        if (lo <= L && L <= hi) {
            P.l1[np] = a; P.l2[np] = b; P.off[np] = off;
            off += (2 * a + 1) * (2 * b + 1) * (2 * L + 1);
            ++np;
        }
    }
    P.np = np; P.total = off;
    return P;
}

// npairs: L0=4, L1=9, L2=11, L3=10.  Floats per n preceding region L:
constexpr int cum_floats(int L) {
    int acc = 0;
    for (int l = 0; l < L; ++l) acc += 2 * (2 * l + 1) * 256 * plist(l).np;
    return acc;
}

// ---- __constant__ CG tables per L (3436 floats total) -----------------
template <int L> struct CGTabT { float v[plist(L).total]; };

template <int L>
constexpr CGTabT<L> make_cgtab() {
    CGTabT<L> t{};
    constexpr PairList P = plist(L);
    constexpr int zd = 2 * L + 1;
    for (int p = 0; p < P.np; ++p) {
        const int l1 = P.l1[p], l2 = P.l2[p];
        const int yd = 2 * l2 + 1;
        for (int x = 0; x < 2 * l1 + 1; ++x)
            for (int y = 0; y < yd; ++y)
                for (int z = 0; z < zd; ++z)
                    t.v[P.off[p] + (x * yd + y) * zd + z] =
                        (float)cg_coef_c(l1, x - l1, l2, y - l2, L, z - L);
    }
    return t;
}

__constant__ CGTabT<0> CGT0 = make_cgtab<0>();
__constant__ CGTabT<1> CGT1 = make_cgtab<1>();
__constant__ CGTabT<2> CGT2 = make_cgtab<2>();
__constant__ CGTabT<3> CGT3 = make_cgtab<3>();

// ---- segment table: 156 segments per n, ordered (L, z, p) -------------
// tid = global triple id (0..33): L0 pairs 0-3, L1 4-12, L2 13-23, L3 24-33.
struct SegTab { int tid[156]; int z[156]; };

constexpr SegTab make_segtab() {
    SegTab s{};
    int i = 0, tidbase = 0;
    for (int L = 0; L <= 3; ++L) {
        PairList P = plist(L);
        int zd = 2 * L + 1;
        for (int z = 0; z < zd; ++z)
            for (int p = 0; p < P.np; ++p) {
                s.tid[i] = tidbase + p;
                s.z[i]   = z;
                ++i;
            }
        tidbase += P.np;
    }
    return s;
}

__constant__ SegTab SEG = make_segtab();

// ---------------------------------------------------------------------------
// One segment = one (n, L, z, pair): 256 channels, re+im -> 2 x 1KB nt-stores.
// lane -> (c = lane>>2, d4 = (lane&3)*4).  Body math identical to r12 (passed).
// ---------------------------------------------------------------------------
template <int l1, int l2, int L, int p>
__device__ __forceinline__ void seg_body(
    const float* __restrict__ A0, const float* __restrict__ A1,
    const float* __restrict__ A2, const float* __restrict__ A3,
    const float* __restrict__ B0, const float* __restrict__ B1,
    const float* __restrict__ B2, const float* __restrict__ B3,
    float* __restrict__ out, int N, unsigned n, unsigned lane, int z)
{
    constexpr int xdim = 2 * l1 + 1, ydim = 2 * l2 + 1, zdim = 2 * L + 1;
    constexpr int CHL  = 256 * plist(L).np;
    constexpr int CGO  = plist(L).off[p];

    const float* cg = (L == 0) ? CGT0.v : (L == 1) ? CGT1.v
                    : (L == 2) ? CGT2.v : CGT3.v;

    const int s   = z + l1 + l2 - L;
    const int xlo = (s - (ydim - 1) > 0) ? s - (ydim - 1) : 0;
    const int xhi = (s < xdim - 1) ? s : (xdim - 1);

    const unsigned c  = lane >> 2;
    const unsigned d4 = (lane & 3u) << 2;

    const float* Ab = (l1 == 0) ? A0 : (l1 == 1) ? A1 : (l1 == 2) ? A2 : A3;
    const float* Bb = (l2 == 0) ? B0 : (l2 == 1) ? B1 : (l2 == 2) ? B2 : B3;

    const float* Ar = Ab + n * (unsigned)(xdim * 16) + c;
    const float* Ai = Ar + (unsigned)N * (unsigned)(xdim * 16);
    const float* Br = Bb + n * (unsigned)(ydim * 16) + d4;
    const float* Bi = Br + (unsigned)N * (unsigned)(ydim * 16);

    const int cgbase = CGO + s * zdim + z;

    f32x4 accr = {0.f, 0.f, 0.f, 0.f};
    f32x4 acci = {0.f, 0.f, 0.f, 0.f};
    #pragma unroll
    for (int x = 0; x < xdim; ++x) {
        if (x >= xlo && x <= xhi) {                 // wave-uniform guard
            const float cgv = cg[cgbase + x * (ydim - 1) * zdim];
            const float arv = Ar[x * 16], aiv = Ai[x * 16];
            const float car = cgv * arv, cai = cgv * aiv;
            const f32x4 brv = *reinterpret_cast<const f32x4*>(Br + (unsigned)(s - x) * 16u);
            const f32x4 biv = *reinterpret_cast<const f32x4*>(Bi + (unsigned)(s - x) * 16u);
            accr += car * brv - cai * biv;
            acci += car * biv + cai * brv;
        }
    }

    const unsigned base = (unsigned)N * (unsigned)cum_floats(L)
                        + (n * (unsigned)zdim + (unsigned)z) * (unsigned)CHL
                        + (unsigned)(p * 256) + lane * 4u;
    const unsigned imoff = (unsigned)N * (unsigned)(zdim * CHL);
    __builtin_nontemporal_store(accr, reinterpret_cast<f32x4*>(out + base));
    __builtin_nontemporal_store(acci, reinterpret_cast<f32x4*>(out + base + imoff));
}

// One block per n: 512 threads = 8 waves; wave w handles segments w, w+8, ...
__global__ __launch_bounds__(512) void cg_prod_rows(
    const float* __restrict__ A0, const float* __restrict__ A1,
    const float* __restrict__ A2, const float* __restrict__ A3,
    const float* __restrict__ B0, const float* __restrict__ B1,
    const float* __restrict__ B2, const float* __restrict__ B3,
    float* __restrict__ out, int N)
{
    const unsigned n    = blockIdx.x;
    const unsigned wid  = threadIdx.x >> 6;
    const unsigned lane = threadIdx.x & 63u;

#define PB(Lv, BASE, K) case K: \
    seg_body<plist(Lv).l1[K - BASE], plist(Lv).l2[K - BASE], Lv, K - BASE>( \
        A0, A1, A2, A3, B0, B1, B2, B3, out, N, n, lane, z); break;

    for (int t = (int)wid; t < 156; t += 8) {
        const int tid = SEG.tid[t];
        const int z   = SEG.z[t];
        switch (tid) {
            PB(0, 0, 0)   PB(0, 0, 1)   PB(0, 0, 2)   PB(0, 0, 3)
            PB(1, 4, 4)   PB(1, 4, 5)   PB(1, 4, 6)   PB(1, 4, 7)
            PB(1, 4, 8)   PB(1, 4, 9)   PB(1, 4, 10)  PB(1, 4, 11)
            PB(1, 4, 12)
            PB(2, 13, 13) PB(2, 13, 14) PB(2, 13, 15) PB(2, 13, 16)
            PB(2, 13, 17) PB(2, 13, 18) PB(2, 13, 19) PB(2, 13, 20)
            PB(2, 13, 21) PB(2, 13, 22) PB(2, 13, 23)
            PB(3, 24, 24) PB(3, 24, 25) PB(3, 24, 26) PB(3, 24, 27)
            PB(3, 24, 28) PB(3, 24, 29) PB(3, 24, 30) PB(3, 24, 31)
            PB(3, 24, 32) PB(3, 24, 33)
        }
    }
#undef PB
}

extern "C" void kernel_launch(void* const* d_in, const int* in_sizes, int n_in,
                              void* d_out, int out_size, void* d_ws, size_t ws_size,
                              hipStream_t stream) {
    // setup_inputs() dict order is INTERLEAVED: A0,B0,A1,B1,A2,B2,A3,B3
    const float* A0 = (const float*)d_in[0];
    const float* B0 = (const float*)d_in[1];
    const float* A1 = (const float*)d_in[2];
    const float* B1 = (const float*)d_in[3];
    const float* A2 = (const float*)d_in[4];
    const float* B2 = (const float*)d_in[5];
    const float* A3 = (const float*)d_in[6];
    const float* B3 = (const float*)d_in[7];
    float* out = (float*)d_out;
    (void)d_ws; (void)ws_size;

    const int N = in_sizes[0] / 32;  // A0 is (2, N, 1, 16)

    // One block per n; 8 waves/block; each wave ~19-20 segments.
    hipLaunchKernelGGL(cg_prod_rows, dim3(N), dim3(512), 0, stream,
                       A0, A1, A2, A3, B0, B1, B2, B3, out, N);
}